// Round 2
// baseline (997.968 us; speedup 1.0000x reference)
//
#include <hip/hip_runtime.h>

#define HIDDEN 64
#define INFEAT 128
#define SCALE_C 0.70710678118654752f
#define BN_EPS 1e-5f

// ---------- degree histogram ----------
__global__ void k_deg(const int* __restrict__ src, const int* __restrict__ dst,
                      float* __restrict__ deg_out, float* __restrict__ deg_in, int E){
  int e = blockIdx.x * blockDim.x + threadIdx.x;
  if (e < E){
    atomicAdd(&deg_out[src[e]], 1.0f);
    atomicAdd(&deg_in[dst[e]], 1.0f);
  }
}

// deg -> rsqrt(max(deg,1)) in place
__global__ void k_norm(float* __restrict__ deg_out, float* __restrict__ deg_in, int N){
  int n = blockIdx.x * blockDim.x + threadIdx.x;
  if (n < N){
    deg_out[n] = rsqrtf(fmaxf(deg_out[n], 1.0f));
    deg_in[n]  = rsqrtf(fmaxf(deg_in[n], 1.0f));
  }
}

// ---------- fc: h = x @ fc_w + fc_b   (x f32 [N][128], W f32 [128][64]) ----------
// One wave per node; lane = output column; W staged in LDS; x row broadcast from L1.
__global__ __launch_bounds__(256) void k_fc(const float* __restrict__ x,
    const float* __restrict__ W, const float* __restrict__ bias,
    float* __restrict__ h, int N){
  __shared__ float Wl[INFEAT * HIDDEN];   // 32 KB
  int tid = threadIdx.x;
  for (int i = tid; i < INFEAT * HIDDEN; i += 256) Wl[i] = W[i];
  __syncthreads();
  int wave = tid >> 6, lane = tid & 63;
  float bv = bias[lane];
  for (long node = (long)blockIdx.x * 4 + wave; node < N; node += (long)gridDim.x * 4){
    const float4* xr = (const float4*)(x + node * INFEAT);
    float acc = 0.f;
    #pragma unroll
    for (int k0 = 0; k0 < INFEAT; k0 += 4){
      float4 u = xr[k0 >> 2];                   // same addr across wave -> L1 broadcast
      const float* wr = &Wl[k0 * HIDDEN + lane];
      acc = fmaf(u.x, wr[0],   acc);
      acc = fmaf(u.y, wr[64],  acc);
      acc = fmaf(u.z, wr[128], acc);
      acc = fmaf(u.w, wr[192], acc);
    }
    h[node * HIDDEN + lane] = acc + bv;
  }
}

// ---------- t = h @ w   (h f32 [N][64], w f32 [64][64]) -> t f32 ----------
__global__ __launch_bounds__(256) void k_hw(const float* __restrict__ hin,
    const float* __restrict__ W, float* __restrict__ t, int N){
  __shared__ float Wl[HIDDEN * HIDDEN];   // 16 KB
  int tid = threadIdx.x;
  for (int i = tid; i < HIDDEN * HIDDEN; i += 256) Wl[i] = W[i];
  __syncthreads();
  int wave = tid >> 6, lane = tid & 63;
  for (long node = (long)blockIdx.x * 4 + wave; node < N; node += (long)gridDim.x * 4){
    const float4* hr = (const float4*)(hin + node * HIDDEN);
    float acc = 0.f;
    #pragma unroll
    for (int k0 = 0; k0 < HIDDEN; k0 += 4){
      float4 a = hr[k0 >> 2];                   // broadcast from L1
      const float* wr = &Wl[k0 * HIDDEN + lane];
      acc = fmaf(a.x, wr[0],   acc);
      acc = fmaf(a.y, wr[64],  acc);
      acc = fmaf(a.z, wr[128], acc);
      acc = fmaf(a.w, wr[192], acc);
    }
    t[node * HIDDEN + lane] = acc;
  }
}

// ---------- edge scatter: agg[dst] += t[src] * norm_out[src]  (one wave per edge) ----------
__global__ __launch_bounds__(256) void k_scatter(const int* __restrict__ src, const int* __restrict__ dst,
    const float* __restrict__ t, const float* __restrict__ norm_out,
    float* __restrict__ agg, int E){
  int lane = threadIdx.x & 63;
  int e = blockIdx.x * 4 + (threadIdx.x >> 6);
  if (e < E){
    int s = src[e], d = dst[e];
    float v = t[(long)s * HIDDEN + lane] * norm_out[s];
    atomicAdd(&agg[(long)d * HIDDEN + lane], v);
  }
}

// ---------- residual combine: h = (h + agg*norm_in[node] + b[col]) * SCALE ----------
__global__ void k_combine(float* __restrict__ h, const float* __restrict__ agg,
    const float* __restrict__ norm_in, const float* __restrict__ b, int N){
  long i = (long)blockIdx.x * blockDim.x + threadIdx.x;
  long total = (long)N * HIDDEN;
  if (i < total){
    long node = i >> 6; int col = (int)(i & 63);
    h[i] = (h[i] + agg[i] * norm_in[node] + b[col]) * SCALE_C;
  }
}

// ---------- combine + BN partial sums (per-block, no atomics) ----------
__global__ __launch_bounds__(256) void k_combine_bn(float* __restrict__ h, const float* __restrict__ agg,
    const float* __restrict__ norm_in, const float* __restrict__ b,
    float* __restrict__ bnpart, int N){
  int tid = threadIdx.x;
  long total = (long)N * HIDDEN;
  long stride = (long)gridDim.x * 256;          // multiple of 64 -> col fixed per thread
  float bv = b[tid & 63];
  float s1 = 0.f, s2 = 0.f;
  for (long i = (long)blockIdx.x * 256 + tid; i < total; i += stride){
    long node = i >> 6;
    float v = (h[i] + agg[i] * norm_in[node] + bv) * SCALE_C;
    h[i] = v;
    s1 += v; s2 += v * v;
  }
  __shared__ float l1[256], l2[256];
  l1[tid] = s1; l2[tid] = s2;
  __syncthreads();
  if (tid < 64){
    float a1 = l1[tid] + l1[tid+64] + l1[tid+128] + l1[tid+192];
    float a2 = l2[tid] + l2[tid+64] + l2[tid+128] + l2[tid+192];
    bnpart[blockIdx.x * 128 + tid] = a1;
    bnpart[blockIdx.x * 128 + 64 + tid] = a2;
  }
}

// ---------- BN finalize: per-column scale/shift ----------
__global__ void k_bnfin(const float* __restrict__ bnpart,
    const float* __restrict__ gamma, const float* __restrict__ beta,
    float* __restrict__ bnab, int nblk, float invN){
  int c = threadIdx.x;  // 64 threads
  float s1 = 0.f, s2 = 0.f;
  for (int b = 0; b < nblk; ++b){ s1 += bnpart[b*128 + c]; s2 += bnpart[b*128 + 64 + c]; }
  float mu  = s1 * invN;
  float var = s2 * invN - mu * mu;               // biased variance
  float rstd = rsqrtf(var + BN_EPS);
  float sc = gamma[c] * rstd;
  bnab[c] = sc;
  bnab[64 + c] = beta[c] - mu * sc;
}

// ---------- BN apply (in place on h == d_out) ----------
__global__ void k_bnapply(float* __restrict__ h, const float* __restrict__ bnab, int N){
  long i = (long)blockIdx.x * blockDim.x + threadIdx.x;
  long total = (long)N * HIDDEN;
  if (i < total){
    int c = (int)(i & 63);
    h[i] = fmaf(h[i], bnab[c], bnab[64 + c]);
  }
}

extern "C" void kernel_launch(void* const* d_in, const int* in_sizes, int n_in,
                              void* d_out, int out_size, void* d_ws, size_t ws_size,
                              hipStream_t stream){
  const int* src = (const int*)d_in[0];
  const int* dst = (const int*)d_in[1];
  const float* x     = (const float*)d_in[2];
  const float* fc_w  = (const float*)d_in[3];
  const float* fc_b  = (const float*)d_in[4];
  const float* w1    = (const float*)d_in[5];
  const float* b1    = (const float*)d_in[6];
  const float* w2    = (const float*)d_in[7];
  const float* b2    = (const float*)d_in[8];
  const float* gamma = (const float*)d_in[9];
  const float* beta  = (const float*)d_in[10];
  const int E = in_sizes[0];
  const int N = in_sizes[2] / INFEAT;

  // h lives in d_out (fully overwritten by k_fc before any read; BN apply is in-place)
  float* h = (float*)d_out;

  // workspace carve (~52 MB)
  float* agg      = (float*)d_ws;                 // N*64 f32
  float* t        = agg + (size_t)N * HIDDEN;     // N*64 f32
  float* norm_out = t + (size_t)N * HIDDEN;       // N f32
  float* norm_in  = norm_out + N;                 // N f32
  float* bnpart   = norm_in + N;                  // 256*128 f32
  float* bnab     = bnpart + 256 * 128;           // 128 f32

  // degrees + norms
  hipMemsetAsync(norm_out, 0, 2 * (size_t)N * sizeof(float), stream);
  k_deg<<<(E + 255) / 256, 256, 0, stream>>>(src, dst, norm_out, norm_in, E);
  k_norm<<<(N + 255) / 256, 256, 0, stream>>>(norm_out, norm_in, N);

  // fc
  k_fc<<<2500, 256, 0, stream>>>(x, fc_w, fc_b, h, N);

  // conv1
  k_hw<<<2500, 256, 0, stream>>>(h, w1, t, N);
  hipMemsetAsync(agg, 0, (size_t)N * HIDDEN * sizeof(float), stream);
  k_scatter<<<(E + 3) / 4, 256, 0, stream>>>(src, dst, t, norm_out, agg, E);
  k_combine<<<(int)(((long)N * HIDDEN + 255) / 256), 256, 0, stream>>>(h, agg, norm_in, b1, N);

  // conv2
  k_hw<<<2500, 256, 0, stream>>>(h, w2, t, N);
  hipMemsetAsync(agg, 0, (size_t)N * HIDDEN * sizeof(float), stream);
  k_scatter<<<(E + 3) / 4, 256, 0, stream>>>(src, dst, t, norm_out, agg, E);
  k_combine_bn<<<256, 256, 0, stream>>>(h, agg, norm_in, b2, bnpart, N);

  // batchnorm
  k_bnfin<<<1, 64, 0, stream>>>(bnpart, gamma, beta, bnab, 256, 1.0f / (float)N);
  k_bnapply<<<(int)(((long)N * HIDDEN + 255) / 256), 256, 0, stream>>>(h, bnab, N);
}

// Round 3
// 758.456 us; speedup vs baseline: 1.3158x; 1.3158x over previous
//
#include <hip/hip_runtime.h>

#define HIDDEN 64
#define INFEAT 128
#define SCALE_C 0.70710678118654752f
#define BN_EPS 1e-5f

// ---------- degree histogram ----------
__global__ void k_deg(const int* __restrict__ src, const int* __restrict__ dst,
                      float* __restrict__ deg_out, float* __restrict__ deg_in, int E){
  int e = blockIdx.x * blockDim.x + threadIdx.x;
  if (e < E){
    atomicAdd(&deg_out[src[e]], 1.0f);
    atomicAdd(&deg_in[dst[e]], 1.0f);
  }
}

// deg -> rsqrt(max(deg,1)) in place
__global__ void k_norm(float* __restrict__ deg_out, float* __restrict__ deg_in, int N){
  int n = blockIdx.x * blockDim.x + threadIdx.x;
  if (n < N){
    deg_out[n] = rsqrtf(fmaxf(deg_out[n], 1.0f));
    deg_in[n]  = rsqrtf(fmaxf(deg_in[n], 1.0f));
  }
}

// ---------- GEMM: Y[N][64] = X[N][KDIM] @ W[KDIM][64] (+B) ----------
// 128 nodes/block (256 thr). lane = node, wave-half owns 32 output cols.
// X tile staged in LDS (coalesced global loads, stride-33 = conflict-free).
// W read at wave-uniform addresses -> scalar loads (SGPR operand on v_fmac).
template<int KDIM, bool ADDB>
__global__ __launch_bounds__(256) void k_gemm(const float* __restrict__ X,
    const float* __restrict__ W, const float* __restrict__ B,
    float* __restrict__ Y, int N)
{
  __shared__ float xl[128 * 33];
  const int tid  = threadIdx.x;
  const int lane = tid & 63;
  const int wid  = __builtin_amdgcn_readfirstlane(tid >> 6);  // wave-uniform
  const int nodehalf = wid >> 1;               // 0/1
  const int c0 = (wid & 1) * 32;               // column offset (uniform)
  const int base = blockIdx.x * 128;
  const int myNode = nodehalf * 64 + lane;     // 0..127
  const int gnode = base + myNode;

  float acc[32];
  #pragma unroll
  for (int c = 0; c < 32; ++c) acc[c] = ADDB ? B[c0 + c] : 0.f;  // uniform -> s_load

  constexpr int NCHUNK = KDIM / 32;
  #pragma unroll 1
  for (int ck = 0; ck < NCHUNK; ++ck){
    __syncthreads();                 // previous chunk's readers done
    #pragma unroll
    for (int i = 0; i < 4; ++i){
      int f  = i * 256 + tid;        // float4 id, 0..1023
      int nd = f >> 3;               // 0..127
      int kq = f & 7;                // 0..7
      float4 v = make_float4(0.f, 0.f, 0.f, 0.f);
      if (base + nd < N)
        v = *(const float4*)(X + (size_t)(base + nd) * KDIM + ck * 32 + kq * 4);
      float* p = &xl[nd * 33 + kq * 4];
      p[0] = v.x; p[1] = v.y; p[2] = v.z; p[3] = v.w;
    }
    __syncthreads();
    const float* wrow = W + (size_t)ck * 32 * HIDDEN + c0;   // uniform base
    #pragma unroll
    for (int k = 0; k < 32; ++k){
      float xv = xl[myNode * 33 + k];
      #pragma unroll
      for (int c = 0; c < 32; ++c)
        acc[c] = fmaf(xv, wrow[k * HIDDEN + c], acc[c]);     // W via s_load
    }
  }

  if (gnode < N){
    float4* yp = (float4*)(Y + (size_t)gnode * HIDDEN + c0);
    #pragma unroll
    for (int j = 0; j < 8; ++j)
      yp[j] = make_float4(acc[4*j], acc[4*j+1], acc[4*j+2], acc[4*j+3]);
  }
}

// ---------- edge scatter: agg[dst] += t[src] * norm_out[src]  (one wave per edge) ----------
__global__ __launch_bounds__(256) void k_scatter(const int* __restrict__ src, const int* __restrict__ dst,
    const float* __restrict__ t, const float* __restrict__ norm_out,
    float* __restrict__ agg, int E){
  int lane = threadIdx.x & 63;
  int e = blockIdx.x * 4 + (threadIdx.x >> 6);
  if (e < E){
    int s = src[e], d = dst[e];
    float v = t[(long)s * HIDDEN + lane] * norm_out[s];
    atomicAdd(&agg[(long)d * HIDDEN + lane], v);
  }
}

// ---------- residual combine: h = (h + agg*norm_in[node] + b[col]) * SCALE ----------
__global__ void k_combine(float* __restrict__ h, const float* __restrict__ agg,
    const float* __restrict__ norm_in, const float* __restrict__ b, int N){
  long i = (long)blockIdx.x * blockDim.x + threadIdx.x;
  long total = (long)N * HIDDEN;
  if (i < total){
    long node = i >> 6; int col = (int)(i & 63);
    h[i] = (h[i] + agg[i] * norm_in[node] + b[col]) * SCALE_C;
  }
}

// ---------- combine + BN partial sums (per-block, no atomics) ----------
__global__ __launch_bounds__(256) void k_combine_bn(float* __restrict__ h, const float* __restrict__ agg,
    const float* __restrict__ norm_in, const float* __restrict__ b,
    float* __restrict__ bnpart, int N){
  int tid = threadIdx.x;
  long total = (long)N * HIDDEN;
  long stride = (long)gridDim.x * 256;          // multiple of 64 -> col fixed per thread
  float bv = b[tid & 63];
  float s1 = 0.f, s2 = 0.f;
  for (long i = (long)blockIdx.x * 256 + tid; i < total; i += stride){
    long node = i >> 6;
    float v = (h[i] + agg[i] * norm_in[node] + bv) * SCALE_C;
    h[i] = v;
    s1 += v; s2 += v * v;
  }
  __shared__ float l1[256], l2[256];
  l1[tid] = s1; l2[tid] = s2;
  __syncthreads();
  if (tid < 64){
    float a1 = l1[tid] + l1[tid+64] + l1[tid+128] + l1[tid+192];
    float a2 = l2[tid] + l2[tid+64] + l2[tid+128] + l2[tid+192];
    bnpart[blockIdx.x * 128 + tid] = a1;
    bnpart[blockIdx.x * 128 + 64 + tid] = a2;
  }
}

// ---------- BN finalize: per-column scale/shift ----------
__global__ void k_bnfin(const float* __restrict__ bnpart,
    const float* __restrict__ gamma, const float* __restrict__ beta,
    float* __restrict__ bnab, int nblk, float invN){
  int c = threadIdx.x;  // 64 threads
  float s1 = 0.f, s2 = 0.f;
  for (int b = 0; b < nblk; ++b){ s1 += bnpart[b*128 + c]; s2 += bnpart[b*128 + 64 + c]; }
  float mu  = s1 * invN;
  float var = s2 * invN - mu * mu;               // biased variance
  float rstd = rsqrtf(var + BN_EPS);
  float sc = gamma[c] * rstd;
  bnab[c] = sc;
  bnab[64 + c] = beta[c] - mu * sc;
}

// ---------- BN apply (in place on h == d_out) ----------
__global__ void k_bnapply(float* __restrict__ h, const float* __restrict__ bnab, int N){
  long i = (long)blockIdx.x * blockDim.x + threadIdx.x;
  long total = (long)N * HIDDEN;
  if (i < total){
    int c = (int)(i & 63);
    h[i] = fmaf(h[i], bnab[c], bnab[64 + c]);
  }
}

extern "C" void kernel_launch(void* const* d_in, const int* in_sizes, int n_in,
                              void* d_out, int out_size, void* d_ws, size_t ws_size,
                              hipStream_t stream){
  const int* src = (const int*)d_in[0];
  const int* dst = (const int*)d_in[1];
  const float* x     = (const float*)d_in[2];
  const float* fc_w  = (const float*)d_in[3];
  const float* fc_b  = (const float*)d_in[4];
  const float* w1    = (const float*)d_in[5];
  const float* b1    = (const float*)d_in[6];
  const float* w2    = (const float*)d_in[7];
  const float* b2    = (const float*)d_in[8];
  const float* gamma = (const float*)d_in[9];
  const float* beta  = (const float*)d_in[10];
  const int E = in_sizes[0];
  const int N = in_sizes[2] / INFEAT;

  // h lives in d_out (fully overwritten before any read; BN apply in-place)
  float* h = (float*)d_out;

  // workspace carve (~52 MB)
  float* agg      = (float*)d_ws;                 // N*64 f32
  float* t        = agg + (size_t)N * HIDDEN;     // N*64 f32
  float* norm_out = t + (size_t)N * HIDDEN;       // N f32
  float* norm_in  = norm_out + N;                 // N f32
  float* bnpart   = norm_in + N;                  // 256*128 f32
  float* bnab     = bnpart + 256 * 128;           // 128 f32

  const int gemm_grid = (N + 127) / 128;

  // degrees + norms
  hipMemsetAsync(norm_out, 0, 2 * (size_t)N * sizeof(float), stream);
  k_deg<<<(E + 255) / 256, 256, 0, stream>>>(src, dst, norm_out, norm_in, E);
  k_norm<<<(N + 255) / 256, 256, 0, stream>>>(norm_out, norm_in, N);

  // fc (adds fc_b)
  k_gemm<INFEAT, true><<<gemm_grid, 256, 0, stream>>>(x, fc_w, fc_b, h, N);

  // conv1 (bias b1 added in combine, after dst-norm)
  k_gemm<HIDDEN, false><<<gemm_grid, 256, 0, stream>>>(h, w1, nullptr, t, N);
  hipMemsetAsync(agg, 0, (size_t)N * HIDDEN * sizeof(float), stream);
  k_scatter<<<(E + 3) / 4, 256, 0, stream>>>(src, dst, t, norm_out, agg, E);
  k_combine<<<(int)(((long)N * HIDDEN + 255) / 256), 256, 0, stream>>>(h, agg, norm_in, b1, N);

  // conv2
  k_gemm<HIDDEN, false><<<gemm_grid, 256, 0, stream>>>(h, w2, nullptr, t, N);
  hipMemsetAsync(agg, 0, (size_t)N * HIDDEN * sizeof(float), stream);
  k_scatter<<<(E + 3) / 4, 256, 0, stream>>>(src, dst, t, norm_out, agg, E);
  k_combine_bn<<<256, 256, 0, stream>>>(h, agg, norm_in, b2, bnpart, N);

  // batchnorm
  k_bnfin<<<1, 64, 0, stream>>>(bnpart, gamma, beta, bnab, 256, 1.0f / (float)N);
  k_bnapply<<<(int)(((long)N * HIDDEN + 255) / 256), 256, 0, stream>>>(h, bnab, N);
}

// Round 4
// 559.123 us; speedup vs baseline: 1.7849x; 1.3565x over previous
//
#include <hip/hip_runtime.h>

#define HIDDEN 64
#define INFEAT 128
#define SCALE_C 0.70710678118654752f
#define BN_EPS 1e-5f
#define AGG_GRID 2048

// ---------- int degree histograms ----------
__global__ void k_hist(const int* __restrict__ src, const int* __restrict__ dst,
                       int* __restrict__ degO, int* __restrict__ degI, int E){
  int e = blockIdx.x * blockDim.x + threadIdx.x;
  if (e < E){
    atomicAdd(&degO[src[e]], 1);
    atomicAdd(&degI[dst[e]], 1);
  }
}

// ---------- norms from int degrees ----------
__global__ void k_norm(const int* __restrict__ degO, const int* __restrict__ degI,
                       float* __restrict__ norm_out, float* __restrict__ norm_in, int N){
  int n = blockIdx.x * blockDim.x + threadIdx.x;
  if (n < N){
    norm_out[n] = rsqrtf((float)max(degO[n], 1));
    norm_in[n]  = rsqrtf((float)max(degI[n], 1));
  }
}

// ---------- scan step 1: per-256-chunk sums ----------
__global__ void k_scan1(const int* __restrict__ deg, int* __restrict__ bsum, int N){
  __shared__ int sh[256];
  int t = threadIdx.x;
  int i = blockIdx.x * 256 + t;
  sh[t] = (i < N) ? deg[i] : 0;
  __syncthreads();
  for (int ofs = 128; ofs > 0; ofs >>= 1){
    if (t < ofs) sh[t] += sh[t + ofs];
    __syncthreads();
  }
  if (t == 0) bsum[blockIdx.x] = sh[0];
}

// ---------- scan step 2: exclusive scan of block sums (1 block, 512 thr) ----------
__global__ void k_scan2(int* __restrict__ bsum, int NB){
  __shared__ int sh[512];
  int t = threadIdx.x;
  int v = (t < NB) ? bsum[t] : 0;
  sh[t] = v;
  __syncthreads();
  for (int ofs = 1; ofs < 512; ofs <<= 1){
    int u = (t >= ofs) ? sh[t - ofs] : 0;
    __syncthreads();
    sh[t] += u;
    __syncthreads();
  }
  if (t < NB) bsum[t] = sh[t] - v;   // exclusive
}

// ---------- scan step 3: intra-block exclusive scan + offset -> row_ptr, cursor ----------
__global__ void k_scan3(const int* __restrict__ deg, const int* __restrict__ bofs,
                        int* __restrict__ rp, int* __restrict__ cur, int N, int E){
  __shared__ int sh[256];
  int t = threadIdx.x;
  int i = blockIdx.x * 256 + t;
  int v = (i < N) ? deg[i] : 0;
  sh[t] = v;
  __syncthreads();
  for (int ofs = 1; ofs < 256; ofs <<= 1){
    int u = (t >= ofs) ? sh[t - ofs] : 0;
    __syncthreads();
    sh[t] += u;
    __syncthreads();
  }
  if (i < N){
    int excl = sh[t] - v + bofs[blockIdx.x];
    rp[i] = excl; cur[i] = excl;
    if (i == N - 1) rp[N] = E;
  }
}

// ---------- edge placement into CSR buckets ----------
__global__ void k_place(const int* __restrict__ src, const int* __restrict__ dst,
                        int* __restrict__ cur, int* __restrict__ cs, int E){
  int e = blockIdx.x * blockDim.x + threadIdx.x;
  if (e < E){
    int pos = atomicAdd(&cur[dst[e]], 1);
    cs[pos] = src[e];
  }
}

// ---------- GEMM: Y[N][64] = X[N][KDIM] @ W[KDIM][64] (+B) (opt: row scale by nrm) ----------
// 128 nodes/block (256 thr). lane = node, wave-half owns 32 output cols.
// X tile staged in LDS (coalesced, stride-33 conflict-free); W via wave-uniform s_loads.
template<int KDIM, bool ADDB, bool SCALEROW>
__global__ __launch_bounds__(256) void k_gemm(const float* __restrict__ X,
    const float* __restrict__ W, const float* __restrict__ B,
    float* __restrict__ Y, const float* __restrict__ nrm, int N)
{
  __shared__ float xl[128 * 33];
  const int tid  = threadIdx.x;
  const int lane = tid & 63;
  const int wid  = __builtin_amdgcn_readfirstlane(tid >> 6);  // wave-uniform
  const int nodehalf = wid >> 1;               // 0/1
  const int c0 = (wid & 1) * 32;               // column offset (uniform)
  const int base = blockIdx.x * 128;
  const int myNode = nodehalf * 64 + lane;     // 0..127
  const int gnode = base + myNode;

  float acc[32];
  #pragma unroll
  for (int c = 0; c < 32; ++c) acc[c] = ADDB ? B[c0 + c] : 0.f;

  constexpr int NCHUNK = KDIM / 32;
  #pragma unroll 1
  for (int ck = 0; ck < NCHUNK; ++ck){
    __syncthreads();
    #pragma unroll
    for (int i = 0; i < 4; ++i){
      int f  = i * 256 + tid;        // float4 id, 0..1023
      int nd = f >> 3;               // 0..127
      int kq = f & 7;                // 0..7
      float4 v = make_float4(0.f, 0.f, 0.f, 0.f);
      if (base + nd < N)
        v = *(const float4*)(X + (size_t)(base + nd) * KDIM + ck * 32 + kq * 4);
      float* p = &xl[nd * 33 + kq * 4];
      p[0] = v.x; p[1] = v.y; p[2] = v.z; p[3] = v.w;
    }
    __syncthreads();
    const float* wrow = W + (size_t)ck * 32 * HIDDEN + c0;   // uniform base
    #pragma unroll
    for (int k = 0; k < 32; ++k){
      float xv = xl[myNode * 33 + k];
      #pragma unroll
      for (int c = 0; c < 32; ++c)
        acc[c] = fmaf(xv, wrow[k * HIDDEN + c], acc[c]);     // W via s_load
    }
  }

  if (gnode < N){
    float sc = SCALEROW ? nrm[gnode] : 1.f;
    float4* yp = (float4*)(Y + (size_t)gnode * HIDDEN + c0);
    #pragma unroll
    for (int j = 0; j < 8; ++j)
      yp[j] = make_float4(acc[4*j]*sc, acc[4*j+1]*sc, acc[4*j+2]*sc, acc[4*j+3]*sc);
  }
}

// ---------- fused CSR aggregate + residual combine (+ BN partials) ----------
// One wave per dst node (grid-stride). lane = column. t rows already scaled by norm_out.
template<bool BN>
__global__ __launch_bounds__(256) void k_agg(const int* __restrict__ rp, const int* __restrict__ cs,
    const float* __restrict__ t, const float* __restrict__ norm_in,
    const float* __restrict__ b, float* __restrict__ h, float* __restrict__ bnpart, int N)
{
  const int tid = threadIdx.x;
  const int lane = tid & 63;
  const int wv = (blockIdx.x * 256 + tid) >> 6;
  const int nw = (gridDim.x * 256) >> 6;
  const float bv = b[lane];
  float s1 = 0.f, s2 = 0.f;

  for (int n = wv; n < N; n += nw){
    const int start = rp[n], end = rp[n + 1];
    float acc = 0.f;
    for (int j0 = start; j0 < end; j0 += 64){
      int cnt = end - j0; if (cnt > 64) cnt = 64;
      int sidx = (j0 + lane < end) ? cs[j0 + lane] : 0;
      int d = 0;
      for (; d + 4 <= cnt; d += 4){
        int a0 = __shfl(sidx, d),     a1 = __shfl(sidx, d + 1);
        int a2 = __shfl(sidx, d + 2), a3 = __shfl(sidx, d + 3);
        float v0 = t[(size_t)a0 * HIDDEN + lane];
        float v1 = t[(size_t)a1 * HIDDEN + lane];
        float v2 = t[(size_t)a2 * HIDDEN + lane];
        float v3 = t[(size_t)a3 * HIDDEN + lane];
        acc += v0; acc += v1; acc += v2; acc += v3;
      }
      for (; d < cnt; ++d){
        int a0 = __shfl(sidx, d);
        acc += t[(size_t)a0 * HIDDEN + lane];
      }
    }
    size_t idx = (size_t)n * HIDDEN + lane;
    float v = (h[idx] + acc * norm_in[n] + bv) * SCALE_C;
    h[idx] = v;
    if (BN){ s1 += v; s2 += v * v; }
  }

  if (BN){
    __shared__ float l1[256], l2[256];
    l1[tid] = s1; l2[tid] = s2;
    __syncthreads();
    if (tid < 64){
      float a1 = l1[tid] + l1[tid+64] + l1[tid+128] + l1[tid+192];
      float a2 = l2[tid] + l2[tid+64] + l2[tid+128] + l2[tid+192];
      bnpart[blockIdx.x * 128 + tid] = a1;
      bnpart[blockIdx.x * 128 + 64 + tid] = a2;
    }
  }
}

// ---------- BN finalize: per-column scale/shift ----------
__global__ void k_bnfin(const float* __restrict__ bnpart,
    const float* __restrict__ gamma, const float* __restrict__ beta,
    float* __restrict__ bnab, int nblk, float invN){
  int c = threadIdx.x;  // 64 threads
  float s1 = 0.f, s2 = 0.f;
  #pragma unroll 4
  for (int b = 0; b < nblk; ++b){ s1 += bnpart[b*128 + c]; s2 += bnpart[b*128 + 64 + c]; }
  float mu  = s1 * invN;
  float var = s2 * invN - mu * mu;               // biased variance
  float rstd = rsqrtf(var + BN_EPS);
  float sc = gamma[c] * rstd;
  bnab[c] = sc;
  bnab[64 + c] = beta[c] - mu * sc;
}

// ---------- BN apply (in place on h == d_out) ----------
__global__ void k_bnapply(float* __restrict__ h, const float* __restrict__ bnab, int N){
  long i = (long)blockIdx.x * blockDim.x + threadIdx.x;
  long total = (long)N * HIDDEN;
  if (i < total){
    int c = (int)(i & 63);
    h[i] = fmaf(h[i], bnab[c], bnab[64 + c]);
  }
}

extern "C" void kernel_launch(void* const* d_in, const int* in_sizes, int n_in,
                              void* d_out, int out_size, void* d_ws, size_t ws_size,
                              hipStream_t stream){
  const int* src = (const int*)d_in[0];
  const int* dst = (const int*)d_in[1];
  const float* x     = (const float*)d_in[2];
  const float* fc_w  = (const float*)d_in[3];
  const float* fc_b  = (const float*)d_in[4];
  const float* w1    = (const float*)d_in[5];
  const float* b1    = (const float*)d_in[6];
  const float* w2    = (const float*)d_in[7];
  const float* b2    = (const float*)d_in[8];
  const float* gamma = (const float*)d_in[9];
  const float* beta  = (const float*)d_in[10];
  const int E = in_sizes[0];
  const int N = in_sizes[2] / INFEAT;
  const int NB = (N + 255) / 256;               // scan chunks (<=512)

  // h lives in d_out (fully overwritten before any read; BN apply in-place)
  float* h = (float*)d_out;

  // workspace carve (~32 MB)
  float* t        = (float*)d_ws;                       // N*64 f32
  float* norm_out = t + (size_t)N * HIDDEN;             // N
  float* norm_in  = norm_out + N;                       // N
  float* bnpart   = norm_in + N;                        // AGG_GRID*128
  float* bnab     = bnpart + AGG_GRID * 128;            // 128
  int*   degO     = (int*)(bnab + 128);                 // N
  int*   degI     = degO + N;                           // N
  int*   rp       = degI + N;                           // N+1
  int*   cur      = rp + N + 1;                         // N
  int*   bsum     = cur + N;                            // 512
  int*   cs       = bsum + 512;                         // E

  // ---- degrees, norms, CSR build (depends only on src/dst) ----
  hipMemsetAsync(degO, 0, 2 * (size_t)N * sizeof(int), stream);
  k_hist<<<(E + 255) / 256, 256, 0, stream>>>(src, dst, degO, degI, E);
  k_norm<<<(N + 255) / 256, 256, 0, stream>>>(degO, degI, norm_out, norm_in, N);
  k_scan1<<<NB, 256, 0, stream>>>(degI, bsum, N);
  k_scan2<<<1, 512, 0, stream>>>(bsum, NB);
  k_scan3<<<NB, 256, 0, stream>>>(degI, bsum, rp, cur, N, E);
  k_place<<<(E + 255) / 256, 256, 0, stream>>>(src, dst, cur, cs, E);

  const int gemm_grid = (N + 127) / 128;

  // ---- fc (adds fc_b) ----
  k_gemm<INFEAT, true, false><<<gemm_grid, 256, 0, stream>>>(x, fc_w, fc_b, h, nullptr, N);

  // ---- conv1: t = (h@w1) * norm_out ; h = (h + gather(t) * norm_in + b1) * sqrt(1/2) ----
  k_gemm<HIDDEN, false, true><<<gemm_grid, 256, 0, stream>>>(h, w1, nullptr, t, norm_out, N);
  k_agg<false><<<AGG_GRID, 256, 0, stream>>>(rp, cs, t, norm_in, b1, h, nullptr, N);

  // ---- conv2 (+ BN partials) ----
  k_gemm<HIDDEN, false, true><<<gemm_grid, 256, 0, stream>>>(h, w2, nullptr, t, norm_out, N);
  k_agg<true><<<AGG_GRID, 256, 0, stream>>>(rp, cs, t, norm_in, b2, h, bnpart, N);

  // ---- batchnorm ----
  k_bnfin<<<1, 64, 0, stream>>>(bnpart, gamma, beta, bnab, AGG_GRID, 1.0f / (float)N);
  k_bnapply<<<(int)(((long)N * HIDDEN + 255) / 256), 256, 0, stream>>>(h, bnab, N);
}

// Round 5
// 419.038 us; speedup vs baseline: 2.3816x; 1.3343x over previous
//
#include <hip/hip_runtime.h>

#define HIDDEN 64
#define INFEAT 128
#define SCALE_C 0.70710678118654752f
#define BN_EPS 1e-5f
#define AGG_GRID 2048
#define RED_BLK 32

// ---------- int degree histograms ----------
__global__ void k_hist(const int* __restrict__ src, const int* __restrict__ dst,
                       int* __restrict__ degO, int* __restrict__ degI, int E){
  int e = blockIdx.x * blockDim.x + threadIdx.x;
  if (e < E){
    atomicAdd(&degO[src[e]], 1);
    atomicAdd(&degI[dst[e]], 1);
  }
}

// ---------- norms from int degrees ----------
__global__ void k_norm(const int* __restrict__ degO, const int* __restrict__ degI,
                       float* __restrict__ norm_out, float* __restrict__ norm_in, int N){
  int n = blockIdx.x * blockDim.x + threadIdx.x;
  if (n < N){
    norm_out[n] = rsqrtf((float)max(degO[n], 1));
    norm_in[n]  = rsqrtf((float)max(degI[n], 1));
  }
}

// ---------- scan step 1: per-256-chunk sums ----------
__global__ void k_scan1(const int* __restrict__ deg, int* __restrict__ bsum, int N){
  __shared__ int sh[256];
  int t = threadIdx.x;
  int i = blockIdx.x * 256 + t;
  sh[t] = (i < N) ? deg[i] : 0;
  __syncthreads();
  for (int ofs = 128; ofs > 0; ofs >>= 1){
    if (t < ofs) sh[t] += sh[t + ofs];
    __syncthreads();
  }
  if (t == 0) bsum[blockIdx.x] = sh[0];
}

// ---------- scan step 2: exclusive scan of block sums (1 block, 512 thr) ----------
__global__ void k_scan2(int* __restrict__ bsum, int NB){
  __shared__ int sh[512];
  int t = threadIdx.x;
  int v = (t < NB) ? bsum[t] : 0;
  sh[t] = v;
  __syncthreads();
  for (int ofs = 1; ofs < 512; ofs <<= 1){
    int u = (t >= ofs) ? sh[t - ofs] : 0;
    __syncthreads();
    sh[t] += u;
    __syncthreads();
  }
  if (t < NB) bsum[t] = sh[t] - v;   // exclusive
}

// ---------- scan step 3: intra-block exclusive scan + offset -> row_ptr, cursor ----------
__global__ void k_scan3(const int* __restrict__ deg, const int* __restrict__ bofs,
                        int* __restrict__ rp, int* __restrict__ cur, int N, int E){
  __shared__ int sh[256];
  int t = threadIdx.x;
  int i = blockIdx.x * 256 + t;
  int v = (i < N) ? deg[i] : 0;
  sh[t] = v;
  __syncthreads();
  for (int ofs = 1; ofs < 256; ofs <<= 1){
    int u = (t >= ofs) ? sh[t - ofs] : 0;
    __syncthreads();
    sh[t] += u;
    __syncthreads();
  }
  if (i < N){
    int excl = sh[t] - v + bofs[blockIdx.x];
    rp[i] = excl; cur[i] = excl;
    if (i == N - 1) rp[N] = E;
  }
}

// ---------- edge placement into CSR buckets ----------
__global__ void k_place(const int* __restrict__ src, const int* __restrict__ dst,
                        int* __restrict__ cur, int* __restrict__ cs, int E){
  int e = blockIdx.x * blockDim.x + threadIdx.x;
  if (e < E){
    int pos = atomicAdd(&cur[dst[e]], 1);
    cs[pos] = src[e];
  }
}

// ---------- GEMM: Y[N][64] = X[N][KDIM] @ W[KDIM][64] (+B) (opt: row scale by nrm) ----------
// 128 nodes/block (256 thr). lane = node, wave-half owns 32 output cols.
// X tile staged in LDS (coalesced, stride-33 conflict-free); W via wave-uniform s_loads.
template<int KDIM, bool ADDB, bool SCALEROW>
__global__ __launch_bounds__(256) void k_gemm(const float* __restrict__ X,
    const float* __restrict__ W, const float* __restrict__ B,
    float* __restrict__ Y, const float* __restrict__ nrm, int N)
{
  __shared__ float xl[128 * 33];
  const int tid  = threadIdx.x;
  const int lane = tid & 63;
  const int wid  = __builtin_amdgcn_readfirstlane(tid >> 6);  // wave-uniform
  const int nodehalf = wid >> 1;               // 0/1
  const int c0 = (wid & 1) * 32;               // column offset (uniform)
  const int base = blockIdx.x * 128;
  const int myNode = nodehalf * 64 + lane;     // 0..127
  const int gnode = base + myNode;

  float acc[32];
  #pragma unroll
  for (int c = 0; c < 32; ++c) acc[c] = ADDB ? B[c0 + c] : 0.f;

  constexpr int NCHUNK = KDIM / 32;
  #pragma unroll 1
  for (int ck = 0; ck < NCHUNK; ++ck){
    __syncthreads();
    #pragma unroll
    for (int i = 0; i < 4; ++i){
      int f  = i * 256 + tid;        // float4 id, 0..1023
      int nd = f >> 3;               // 0..127
      int kq = f & 7;                // 0..7
      float4 v = make_float4(0.f, 0.f, 0.f, 0.f);
      if (base + nd < N)
        v = *(const float4*)(X + (size_t)(base + nd) * KDIM + ck * 32 + kq * 4);
      float* p = &xl[nd * 33 + kq * 4];
      p[0] = v.x; p[1] = v.y; p[2] = v.z; p[3] = v.w;
    }
    __syncthreads();
    const float* wrow = W + (size_t)ck * 32 * HIDDEN + c0;   // uniform base
    #pragma unroll
    for (int k = 0; k < 32; ++k){
      float xv = xl[myNode * 33 + k];
      #pragma unroll
      for (int c = 0; c < 32; ++c)
        acc[c] = fmaf(xv, wrow[k * HIDDEN + c], acc[c]);     // W via s_load
    }
  }

  if (gnode < N){
    float sc = SCALEROW ? nrm[gnode] : 1.f;
    float4* yp = (float4*)(Y + (size_t)gnode * HIDDEN + c0);
    #pragma unroll
    for (int j = 0; j < 8; ++j)
      yp[j] = make_float4(acc[4*j]*sc, acc[4*j+1]*sc, acc[4*j+2]*sc, acc[4*j+3]*sc);
  }
}

// ---------- fused CSR aggregate + residual combine (+ BN partials) ----------
// One wave per dst node (grid-stride). lane = column. t rows already scaled by norm_out.
template<bool BN>
__global__ __launch_bounds__(256) void k_agg(const int* __restrict__ rp, const int* __restrict__ cs,
    const float* __restrict__ t, const float* __restrict__ norm_in,
    const float* __restrict__ b, float* __restrict__ h, float* __restrict__ bnpart, int N)
{
  const int tid = threadIdx.x;
  const int lane = tid & 63;
  const int wv = (blockIdx.x * 256 + tid) >> 6;
  const int nw = (gridDim.x * 256) >> 6;
  const float bv = b[lane];
  float s1 = 0.f, s2 = 0.f;

  for (int n = wv; n < N; n += nw){
    const int start = rp[n], end = rp[n + 1];
    float acc = 0.f;
    for (int j0 = start; j0 < end; j0 += 64){
      int cnt = end - j0; if (cnt > 64) cnt = 64;
      int sidx = (j0 + lane < end) ? cs[j0 + lane] : 0;
      int d = 0;
      for (; d + 4 <= cnt; d += 4){
        int a0 = __shfl(sidx, d),     a1 = __shfl(sidx, d + 1);
        int a2 = __shfl(sidx, d + 2), a3 = __shfl(sidx, d + 3);
        float v0 = t[(size_t)a0 * HIDDEN + lane];
        float v1 = t[(size_t)a1 * HIDDEN + lane];
        float v2 = t[(size_t)a2 * HIDDEN + lane];
        float v3 = t[(size_t)a3 * HIDDEN + lane];
        acc += v0; acc += v1; acc += v2; acc += v3;
      }
      for (; d < cnt; ++d){
        int a0 = __shfl(sidx, d);
        acc += t[(size_t)a0 * HIDDEN + lane];
      }
    }
    size_t idx = (size_t)n * HIDDEN + lane;
    float v = (h[idx] + acc * norm_in[n] + bv) * SCALE_C;
    h[idx] = v;
    if (BN){ s1 += v; s2 += v * v; }
  }

  if (BN){
    __shared__ float l1[256], l2[256];
    l1[tid] = s1; l2[tid] = s2;
    __syncthreads();
    if (tid < 64){
      float a1 = l1[tid] + l1[tid+64] + l1[tid+128] + l1[tid+192];
      float a2 = l2[tid] + l2[tid+64] + l2[tid+128] + l2[tid+192];
      bnpart[blockIdx.x * 128 + tid] = a1;
      bnpart[blockIdx.x * 128 + 64 + tid] = a2;
    }
  }
}

// ---------- BN reduce stage 1: 2048 rows -> RED_BLK rows (coalesced, parallel) ----------
__global__ __launch_bounds__(256) void k_bnred(const float* __restrict__ bnpart,
    float* __restrict__ bnred, int nblk){
  int col  = threadIdx.x & 127;
  int half = threadIdx.x >> 7;                 // 0/1
  int rows = nblk / RED_BLK;                   // rows per block
  int r0 = blockIdx.x * rows;
  float s = 0.f;
  for (int r = half; r < rows; r += 2)
    s += bnpart[(size_t)(r0 + r) * 128 + col];
  __shared__ float sh[256];
  sh[threadIdx.x] = s;
  __syncthreads();
  if (threadIdx.x < 128)
    bnred[blockIdx.x * 128 + threadIdx.x] = sh[threadIdx.x] + sh[threadIdx.x + 128];
}

// ---------- BN finalize: per-column scale/shift (RED_BLK rows only) ----------
__global__ void k_bnfin(const float* __restrict__ bnred,
    const float* __restrict__ gamma, const float* __restrict__ beta,
    float* __restrict__ bnab, float invN){
  int c = threadIdx.x;  // 64 threads
  float s1 = 0.f, s2 = 0.f;
  #pragma unroll
  for (int b = 0; b < RED_BLK; ++b){ s1 += bnred[b*128 + c]; s2 += bnred[b*128 + 64 + c]; }
  float mu  = s1 * invN;
  float var = s2 * invN - mu * mu;               // biased variance
  float rstd = rsqrtf(var + BN_EPS);
  float sc = gamma[c] * rstd;
  bnab[c] = sc;
  bnab[64 + c] = beta[c] - mu * sc;
}

// ---------- BN apply (in place on h == d_out) ----------
__global__ void k_bnapply(float* __restrict__ h, const float* __restrict__ bnab, int N){
  long i = (long)blockIdx.x * blockDim.x + threadIdx.x;
  long total = (long)N * HIDDEN;
  if (i < total){
    int c = (int)(i & 63);
    h[i] = fmaf(h[i], bnab[c], bnab[64 + c]);
  }
}

extern "C" void kernel_launch(void* const* d_in, const int* in_sizes, int n_in,
                              void* d_out, int out_size, void* d_ws, size_t ws_size,
                              hipStream_t stream){
  const int* src = (const int*)d_in[0];
  const int* dst = (const int*)d_in[1];
  const float* x     = (const float*)d_in[2];
  const float* fc_w  = (const float*)d_in[3];
  const float* fc_b  = (const float*)d_in[4];
  const float* w1    = (const float*)d_in[5];
  const float* b1    = (const float*)d_in[6];
  const float* w2    = (const float*)d_in[7];
  const float* b2    = (const float*)d_in[8];
  const float* gamma = (const float*)d_in[9];
  const float* beta  = (const float*)d_in[10];
  const int E = in_sizes[0];
  const int N = in_sizes[2] / INFEAT;
  const int NB = (N + 255) / 256;               // scan chunks (<=512)

  // h lives in d_out (fully overwritten before any read; BN apply in-place)
  float* h = (float*)d_out;

  // workspace carve (~32 MB)
  float* t        = (float*)d_ws;                       // N*64 f32
  float* norm_out = t + (size_t)N * HIDDEN;             // N
  float* norm_in  = norm_out + N;                       // N
  float* bnpart   = norm_in + N;                        // AGG_GRID*128
  float* bnred    = bnpart + AGG_GRID * 128;            // RED_BLK*128
  float* bnab     = bnred + RED_BLK * 128;              // 128
  int*   degO     = (int*)(bnab + 128);                 // N
  int*   degI     = degO + N;                           // N
  int*   rp       = degI + N;                           // N+1
  int*   cur      = rp + N + 1;                         // N
  int*   bsum     = cur + N;                            // 512
  int*   cs       = bsum + 512;                         // E

  // ---- degrees, norms, CSR build (depends only on src/dst) ----
  hipMemsetAsync(degO, 0, 2 * (size_t)N * sizeof(int), stream);
  k_hist<<<(E + 255) / 256, 256, 0, stream>>>(src, dst, degO, degI, E);
  k_norm<<<(N + 255) / 256, 256, 0, stream>>>(degO, degI, norm_out, norm_in, N);
  k_scan1<<<NB, 256, 0, stream>>>(degI, bsum, N);
  k_scan2<<<1, 512, 0, stream>>>(bsum, NB);
  k_scan3<<<NB, 256, 0, stream>>>(degI, bsum, rp, cur, N, E);
  k_place<<<(E + 255) / 256, 256, 0, stream>>>(src, dst, cur, cs, E);

  const int gemm_grid = (N + 127) / 128;

  // ---- fc (adds fc_b) ----
  k_gemm<INFEAT, true, false><<<gemm_grid, 256, 0, stream>>>(x, fc_w, fc_b, h, nullptr, N);

  // ---- conv1: t = (h@w1) * norm_out ; h = (h + gather(t) * norm_in + b1) * sqrt(1/2) ----
  k_gemm<HIDDEN, false, true><<<gemm_grid, 256, 0, stream>>>(h, w1, nullptr, t, norm_out, N);
  k_agg<false><<<AGG_GRID, 256, 0, stream>>>(rp, cs, t, norm_in, b1, h, nullptr, N);

  // ---- conv2 (+ BN partials) ----
  k_gemm<HIDDEN, false, true><<<gemm_grid, 256, 0, stream>>>(h, w2, nullptr, t, norm_out, N);
  k_agg<true><<<AGG_GRID, 256, 0, stream>>>(rp, cs, t, norm_in, b2, h, bnpart, N);

  // ---- batchnorm (two-stage parallel reduction) ----
  k_bnred<<<RED_BLK, 256, 0, stream>>>(bnpart, bnred, AGG_GRID);
  k_bnfin<<<1, 64, 0, stream>>>(bnred, gamma, beta, bnab, 1.0f / (float)N);
  k_bnapply<<<(int)(((long)N * HIDDEN + 255) / 256), 256, 0, stream>>>(h, bnab, N);
}